// Round 4
// baseline (415.721 us; speedup 1.0000x reference)
//
#include <hip/hip_runtime.h>
#include <hip/hip_bf16.h>

// Gate: logits = x[16384,4096] @ W[4096,64]; y = softmax(logits) * top2mask.
// Round 4: all staging through per-wave LDS regions via global_load_lds
// (line-aligned contiguous instructions), manual s_waitcnt vmcnt(N) pipeline
// (x 3-deep, W 2-deep), ZERO barriers in the K-loop. Arithmetic (split8,
// MFMA order, K order) is bit-identical to round 3 -> absmax frozen.

typedef float f32x4 __attribute__((ext_vector_type(4)));
typedef __bf16 bf16x8 __attribute__((ext_vector_type(8)));

#define MFMA16(a, b, c) __builtin_amdgcn_mfma_f32_16x16x32_bf16((a), (b), (c), 0, 0, 0)

__device__ __forceinline__ void gload_lds16(const void* g, void* l) {
  __builtin_amdgcn_global_load_lds((const __attribute__((address_space(1))) void*)g,
                                   (__attribute__((address_space(3))) void*)l, 16, 0, 0);
}

// ---------------- K1: W pre-pass (1 MB, LDS-stage-ready layout) ----------
// Per chunk c (32 k's), 4096 bf16 elems: half nh (32 experts) at +nh*2048.
// Within a half: slot s = ((ntl*2 + h)*4 + q)*16 + ln  (16-B slots), holding
// (h?lo:hi) of W[k=c*32+q*8+j][expert nh*32+ntl*16+ln], j=0..7.
// ds_read of frag (ntl,h,q) is then 16 CONTIGUOUS slots indexed by ln ->
// conflict-free b128 phase groups; staging is linear (slot order).
__global__ __launch_bounds__(256) void k_prep_w(const float* __restrict__ W,
                                                __bf16* __restrict__ wsW) {
  const int c = blockIdx.x;       // 0..127
  const int t = threadIdx.x;
  const int e = t & 63;           // expert
  const int q = t >> 6;           // k-quarter
  const int nh = e >> 5, ntl = (e >> 4) & 1, ln = e & 15;
  bf16x8 hi8, lo8;
#pragma unroll
  for (int j = 0; j < 8; ++j) {
    const float w = W[(size_t)(c * 32 + q * 8 + j) * 64 + e];
    const __bf16 h = (__bf16)w;                 // same arithmetic as round 3
    hi8[j] = h;
    lo8[j] = (__bf16)(w - (float)h);
  }
  __bf16* base = wsW + (size_t)c * 4096 + nh * 2048 + ntl * 1024 + q * 128 + ln * 8;
  *(bf16x8*)base = hi8;
  *(bf16x8*)(base + 512) = lo8;
}

// exact truncation split (identical to round 3)
__device__ __forceinline__ void split8(const f32x4 a, const f32x4 b,
                                       bf16x8& hi, bf16x8& lo) {
  const float f[8] = {a.x, a.y, a.z, a.w, b.x, b.y, b.z, b.w};
#pragma unroll
  for (int i = 0; i < 8; ++i) {
    const unsigned u = __builtin_bit_cast(unsigned, f[i]);
    hi[i] = __builtin_bit_cast(__bf16, (unsigned short)(u >> 16));
    lo[i] = (__bf16)(f[i] - __builtin_bit_cast(float, u & 0xFFFF0000u));
  }
}

// ---------------- fused gate kernel --------------------------------------
// Grid 512 x 256 (2 WG/CU). WG = 32 tokens; wave w: mt=w&1 (rows mt*16..+15),
// nh=w>>1 (experts nh*32..+31). Per-wave LDS: x 3 bufs x 2 KB, W 2 bufs x 4 KB.
// x LDS swizzle: slot s(r,g) = r*8 + (g ^ (r&7)), r=wave-local row, g=16B group.
__global__ __launch_bounds__(256, 2) void k_gate(const float* __restrict__ x,
                                                 const __bf16* __restrict__ wsW,
                                                 float* __restrict__ y,
                                                 float* __restrict__ logits) {
  __shared__ __align__(16) char smem[57344];  // [0,24K) x-bufs, [24K,56K) W-bufs
  const int t = threadIdx.x, w = t >> 6, l = t & 63;
  const int tb = blockIdx.x * 32;
  const int mt = w & 1, nh = w >> 1;
  const int q = l >> 4, ln = l & 15;

  char* xw = smem + w * 6144;
  char* ww = smem + 24576 + w * 8192;

  // x staging sources: instr k covers wave-local rows k*8..k*8+7, lane l ->
  // slot s = k*64+l: row r = s>>3, physical group = s&7, logical g = (s&7)^(r&7)
  const int r0 = l >> 3, g0 = (l & 7) ^ (r0 & 7);
  const int r1 = 8 + (l >> 3), g1 = (l & 7) ^ (r1 & 7);
  const float* xp0 = x + (size_t)(tb + mt * 16 + r0) * 4096 + g0 * 4;
  const float* xp1 = x + (size_t)(tb + mt * 16 + r1) * 4096 + g1 * 4;
  const __bf16* wg = wsW + nh * 2048 + l * 8;  // + j*512 + c*4096

  // A-frag ds_read offsets: row rA=ln, k-groups 2q, 2q+1 (swizzled)
  const int rA = ln;
  const int offA0 = (rA * 8 + ((2 * q) ^ (rA & 7))) * 16;
  const int offA1 = (rA * 8 + ((2 * q + 1) ^ (rA & 7))) * 16;
  const int offW = q * 256 + ln * 16;

  auto stageX = [&](int st, int c) {
    char* d = xw + st * 2048 + l * 16;
    gload_lds16(xp0 + (size_t)c * 32, d);
    gload_lds16(xp1 + (size_t)c * 32, d + 1024);
  };
  auto stageW = [&](int st, int c) {
    char* d = ww + st * 4096 + l * 16;
    const __bf16* s = wg + (size_t)c * 4096;
    gload_lds16(s, d);
    gload_lds16(s + 512, d + 1024);
    gload_lds16(s + 1024, d + 2048);
    gload_lds16(s + 1536, d + 3072);
  };

  f32x4 acc0 = {0.f, 0.f, 0.f, 0.f};
  f32x4 acc1 = {0.f, 0.f, 0.f, 0.f};

  // prologue issue order: x0 W0 x1 W1 x2  (steady wait retires x(c),W(c))
  stageX(0, 0); stageW(0, 0); stageX(1, 1); stageW(1, 1); stageX(2, 2);

  int st = 0, stw = 0;
  for (int c = 0; c < 128; ++c) {
    // retire chunk c's loads; keep later chunks (8 groups outstanding steady)
    if (c < 126)       asm volatile("s_waitcnt vmcnt(8)" ::: "memory");
    else if (c == 126) asm volatile("s_waitcnt vmcnt(6)" ::: "memory");
    else               asm volatile("s_waitcnt vmcnt(0)" ::: "memory");

    const char* xb = xw + st * 2048;
    const char* wb = ww + stw * 4096;
    const f32x4 A = *(const f32x4*)(xb + offA0);   // k = q*8..+3
    const f32x4 B = *(const f32x4*)(xb + offA1);   // k = q*8+4..+7
    const bf16x8 wh0 = *(const bf16x8*)(wb + offW);
    const bf16x8 wl0 = *(const bf16x8*)(wb + offW + 1024);
    const bf16x8 wh1 = *(const bf16x8*)(wb + offW + 2048);
    const bf16x8 wl1 = *(const bf16x8*)(wb + offW + 3072);

    bf16x8 ah, al;
    split8(A, B, ah, al);
    acc0 = MFMA16(ah, wh0, acc0);   // identical order to round 3
    acc0 = MFMA16(al, wh0, acc0);
    acc0 = MFMA16(ah, wl0, acc0);
    acc0 = MFMA16(al, wl0, acc0);
    acc1 = MFMA16(ah, wh1, acc1);
    acc1 = MFMA16(al, wh1, acc1);
    acc1 = MFMA16(ah, wl1, acc1);
    acc1 = MFMA16(al, wl1, acc1);

    if (c < 126) stageW(stw, c + 2);      // (c+2)&1 == stw
    if (c < 125) stageX(st, c + 3);       // (c+3)%3 == st
    st = (st == 2) ? 0 : st + 1;
    stw ^= 1;
  }

  // ---------------- epilogue: softmax + top-2 ----------------------------
  __syncthreads();                  // all waves done with staging buffers
  float* lt = (float*)smem;         // overlay 32x65 fp32 tile
  const int col = nh * 32 + ln;
#pragma unroll
  for (int r = 0; r < 4; ++r) {
    const int row = mt * 16 + q * 4 + r;
    lt[row * 65 + col] = acc0[r];
    lt[row * 65 + col + 16] = acc1[r];
    logits[(size_t)(tb + row) * 64 + col] = acc0[r];
    logits[(size_t)(tb + row) * 64 + col + 16] = acc1[r];
  }
  __syncthreads();

#pragma unroll
  for (int i = 0; i < 8; ++i) {
    const int tok = w * 8 + i;
    const float v = lt[tok * 65 + l];
    float bv = v; int bi = l;
    for (int off = 32; off; off >>= 1) {
      const float ov = __shfl_xor(bv, off);
      const int oi = __shfl_xor(bi, off);
      if (ov > bv || (ov == bv && oi < bi)) { bv = ov; bi = oi; }
    }
    const int i1 = bi;
    const float m1 = bv;
    float cv = (l == i1) ? -3.402823466e38f : v;
    int ci = l;
    for (int off = 32; off; off >>= 1) {
      const float ov = __shfl_xor(cv, off);
      const int oi = __shfl_xor(ci, off);
      if (ov > cv || (ov == cv && oi < ci)) { cv = ov; ci = oi; }
    }
    const float e = __expf(v - m1);
    float s = e;
    for (int off = 32; off; off >>= 1) s += __shfl_xor(s, off);
    y[(size_t)(tb + tok) * 64 + l] = (l == i1 || l == ci) ? (e / s) : 0.0f;
  }
}

// ---------------- launcher ------------------------------------------------
extern "C" void kernel_launch(void* const* d_in, const int* in_sizes, int n_in,
                              void* d_out, int out_size, void* d_ws, size_t ws_size,
                              hipStream_t stream) {
  (void)in_sizes; (void)n_in; (void)out_size; (void)ws_size;
  const float* x = (const float*)d_in[0];
  const float* W = (const float*)d_in[1];
  float* out = (float*)d_out;
  float* yout = out;                 // [16384,64]
  float* logits = out + 1048576;     // [16384,64]
  __bf16* wsW = (__bf16*)d_ws;       // 1 MB stage-ready bf16 hi/lo W

  k_prep_w<<<128, 256, 0, stream>>>(W, wsW);
  k_gate<<<512, 256, 0, stream>>>(x, wsW, yout, logits);
}

// Round 5
// 401.919 us; speedup vs baseline: 1.0343x; 1.0343x over previous
//
#include <hip/hip_runtime.h>
#include <hip/hip_bf16.h>

// Gate: logits = x[16384,4096] @ W[4096,64]; y = softmax(logits) * top2mask.
// Round 5: m97-style 2-barrier K-loop + high TLP (1024 WGs, 4/CU, 16 waves).
// BM=16 tokens/WG; wave w owns n-tile w (16 experts). x staged to LDS dbuf
// (1 coalesced global_load_lds per staging wave per chunk); W hi/lo B-frags
// loaded global->register one chunk ahead (L2-hot, drained by the barrier).
// Arithmetic bit-identical to rounds 3/4 (same split, same MFMA order).

typedef float f32x4 __attribute__((ext_vector_type(4)));
typedef __bf16 bf16x8 __attribute__((ext_vector_type(8)));

#define MFMA16(a, b, c) __builtin_amdgcn_mfma_f32_16x16x32_bf16((a), (b), (c), 0, 0, 0)

__device__ __forceinline__ void gload_lds16(const void* g, void* l) {
  __builtin_amdgcn_global_load_lds((const __attribute__((address_space(1))) void*)g,
                                   (__attribute__((address_space(3))) void*)l, 16, 0, 0);
}

// ---------------- K1: W pre-pass (1 MB, frag-ready layout) ---------------
// (bit-identical to round 4) Per chunk c: 4096 elems; half nh at +nh*2048,
// tile ntl at +ntl*1024, hi at +0 / lo at +512, then q*128 + ln*8.
__global__ __launch_bounds__(256) void k_prep_w(const float* __restrict__ W,
                                                __bf16* __restrict__ wsW) {
  const int c = blockIdx.x;       // 0..127
  const int t = threadIdx.x;
  const int e = t & 63;           // expert
  const int q = t >> 6;           // k-quarter
  const int nh = e >> 5, ntl = (e >> 4) & 1, ln = e & 15;
  bf16x8 hi8, lo8;
#pragma unroll
  for (int j = 0; j < 8; ++j) {
    const float w = W[(size_t)(c * 32 + q * 8 + j) * 64 + e];
    const __bf16 h = (__bf16)w;
    hi8[j] = h;
    lo8[j] = (__bf16)(w - (float)h);
  }
  __bf16* base = wsW + (size_t)c * 4096 + nh * 2048 + ntl * 1024 + q * 128 + ln * 8;
  *(bf16x8*)base = hi8;
  *(bf16x8*)(base + 512) = lo8;
}

// exact truncation split (bit-identical to rounds 3/4)
__device__ __forceinline__ void split8(const f32x4 a, const f32x4 b,
                                       bf16x8& hi, bf16x8& lo) {
  const float f[8] = {a.x, a.y, a.z, a.w, b.x, b.y, b.z, b.w};
#pragma unroll
  for (int i = 0; i < 8; ++i) {
    const unsigned u = __builtin_bit_cast(unsigned, f[i]);
    hi[i] = __builtin_bit_cast(__bf16, (unsigned short)(u >> 16));
    lo[i] = (__bf16)(f[i] - __builtin_bit_cast(float, u & 0xFFFF0000u));
  }
}

// ---------------- fused gate kernel --------------------------------------
// Grid 1024 x 256. WG = 16 tokens; wave w = n-tile w (experts w*16..+15).
// x LDS (per buf, 2 KB): slot s = r*8 + p (16-B units), phys group p holds
// logical k-group g = p ^ (r&7)  -> both staging and A-reads conflict-free.
// A-frag (16x16x32): lane l -> A[m=l&15][k=(l>>4)*8+j]
// C/D: lane l, reg r -> C[row=(l>>4)*4+r][col=l&15]
__global__ __launch_bounds__(256, 4) void k_gate(const float* __restrict__ x,
                                                 const __bf16* __restrict__ wsW,
                                                 float* __restrict__ y,
                                                 float* __restrict__ logits) {
  __shared__ __align__(16) char xs[2][2048];
  __shared__ float lt[16 * 65];

  const int t = threadIdx.x, w = t >> 6, l = t & 63;
  const int tb = blockIdx.x * 16;
  const int q = l >> 4, ln = l & 15;

  // x staging (waves 0,1): lane l -> row r = w*8 + (l>>3), phys group l&7,
  // source logical group g = (l&7) ^ (r&7); dest slot = w*64 + l.
  const int sr = w * 8 + (l >> 3);
  const int sg = (l & 7) ^ (sr & 7);
  const float* xp = x + (size_t)(tb + sr) * 4096 + sg * 4;

  // W B-frag global source for wave w's n-tile (contiguous 1 KB per instr)
  const char* wgp = (const char*)wsW + (w >> 1) * 4096 + (w & 1) * 2048 + q * 256 + ln * 16;

  // A-frag ds_read offsets (row ln, logical groups 2q, 2q+1, swizzled)
  const int offA0 = (ln * 8 + ((2 * q) ^ (ln & 7))) * 16;
  const int offA1 = (ln * 8 + ((2 * q + 1) ^ (ln & 7))) * 16;

  f32x4 acc = {0.f, 0.f, 0.f, 0.f};

  // prologue: stage chunk 0, load W(0) into regs; barrier drains both.
  if (w < 2) gload_lds16(xp, &xs[0][(w * 64 + l) * 16]);
  bf16x8 whc = *(const bf16x8*)(wgp);
  bf16x8 wlc = *(const bf16x8*)(wgp + 1024);
  __syncthreads();

  for (int c = 0; c < 128; ++c) {
    bf16x8 whn, wln;
    if (c + 1 < 128) {
      // next chunk's W frags (L2) + x staging; the end-of-iter barrier's
      // vmcnt(0) drain is their (only) completion guarantee.
      whn = *(const bf16x8*)(wgp + (size_t)(c + 1) * 8192);
      wln = *(const bf16x8*)(wgp + (size_t)(c + 1) * 8192 + 1024);
      if (w < 2) gload_lds16(xp + (size_t)(c + 1) * 32,
                             &xs[(c + 1) & 1][(w * 64 + l) * 16]);
    }
    const char* xb = xs[c & 1];
    const f32x4 A = *(const f32x4*)(xb + offA0);
    const f32x4 B = *(const f32x4*)(xb + offA1);
    bf16x8 ah, al;
    split8(A, B, ah, al);
    acc = MFMA16(ah, whc, acc);    // same product order as rounds 3/4
    acc = MFMA16(al, whc, acc);
    acc = MFMA16(ah, wlc, acc);
    acc = MFMA16(al, wlc, acc);
    __syncthreads();
    whc = whn; wlc = wln;
  }

  // ---------------- epilogue: logits + softmax + top-2 -------------------
  const int col = w * 16 + ln;
#pragma unroll
  for (int r = 0; r < 4; ++r) {
    const int row = q * 4 + r;
    lt[row * 65 + col] = acc[r];
    logits[(size_t)(tb + row) * 64 + col] = acc[r];
  }
  __syncthreads();

#pragma unroll
  for (int i = 0; i < 4; ++i) {
    const int tok = w * 4 + i;
    const float v = lt[tok * 65 + l];
    float bv = v; int bi = l;
    for (int off = 32; off; off >>= 1) {
      const float ov = __shfl_xor(bv, off);
      const int oi = __shfl_xor(bi, off);
      if (ov > bv || (ov == bv && oi < bi)) { bv = ov; bi = oi; }
    }
    const int i1 = bi;
    const float m1 = bv;
    float cv = (l == i1) ? -3.402823466e38f : v;
    int ci = l;
    for (int off = 32; off; off >>= 1) {
      const float ov = __shfl_xor(cv, off);
      const int oi = __shfl_xor(ci, off);
      if (ov > cv || (ov == cv && oi < ci)) { cv = ov; ci = oi; }
    }
    const float e = __expf(v - m1);
    float s = e;
    for (int off = 32; off; off >>= 1) s += __shfl_xor(s, off);
    y[(size_t)(tb + tok) * 64 + l] = (l == i1 || l == ci) ? (e / s) : 0.0f;
  }
}

// ---------------- launcher ------------------------------------------------
extern "C" void kernel_launch(void* const* d_in, const int* in_sizes, int n_in,
                              void* d_out, int out_size, void* d_ws, size_t ws_size,
                              hipStream_t stream) {
  (void)in_sizes; (void)n_in; (void)out_size; (void)ws_size;
  const float* x = (const float*)d_in[0];
  const float* W = (const float*)d_in[1];
  float* out = (float*)d_out;
  float* yout = out;                 // [16384,64]
  float* logits = out + 1048576;     // [16384,64]
  __bf16* wsW = (__bf16*)d_ws;       // 1 MB frag-ready bf16 hi/lo W

  k_prep_w<<<128, 256, 0, stream>>>(W, wsW);
  k_gate<<<1024, 256, 0, stream>>>(x, wsW, yout, logits);
}